// Round 9
// baseline (502.182 us; speedup 1.0000x reference)
//
#include <hip/hip_runtime.h>
#include <math.h>

#define NTOK 16384
#define KD   2048
#define NE   256
#define NCHUNK 64             // K step 32
#define CHUNK_DW 4096         // NE*16 dwords per 16-K chunk image
#define TM 32                 // tokens per block
#define SL 257                // Ls row stride (floats)
#define SAW 68                // per-l A row stride (floats)

typedef float f32x2 __attribute__((ext_vector_type(2)));

__device__ __forceinline__ f32x2 pk_mul_lo(f32x2 a, f32x2 b) {
    f32x2 d;
    asm("v_pk_mul_f32 %0, %1, %2 op_sel:[0,0] op_sel_hi:[1,0]"
        : "=v"(d) : "v"(a), "v"(b));
    return d;
}
__device__ __forceinline__ f32x2 pk_mul_hi(f32x2 a, f32x2 b) {
    f32x2 d;
    asm("v_pk_mul_f32 %0, %1, %2 op_sel:[0,1] op_sel_hi:[1,1]"
        : "=v"(d) : "v"(a), "v"(b));
    return d;
}
__device__ __forceinline__ f32x2 pk_add(f32x2 a, f32x2 b) {
    f32x2 d;
    asm("v_pk_add_f32 %0, %1, %2" : "=v"(d) : "v"(a), "v"(b));
    return d;
}

// ---- kernel 0: pre-transform W into chunked, lane-linear slab image (as r6).
// Slab s = (e>>5)*2 + ((e>>4)&1), slot lane = (e&15)*4 + l.
// Bt[c][s*256 + lane*4 + q] = W[e][16c + 4q + l]
__global__ __launch_bounds__(256) void transform_kernel(
    const float* __restrict__ wgt, float* __restrict__ Bt)
{
    const int c    = blockIdx.x >> 2;
    const int qt   = blockIdx.x & 3;
    const int slot = qt * 256 + threadIdx.x;      // 0..1023
    const int s    = slot >> 6;                   // slab 0..15
    const int lane = slot & 63;
    const int em   = lane >> 2;
    const int l    = lane & 3;
    const int e    = (s >> 1) * 32 + (s & 1) * 16 + em;
    const float* src = wgt + (size_t)e * KD + 16 * c + l;
    float4 v = make_float4(src[0], src[4], src[8], src[12]);   // q = 0..3
    *(float4*)(Bt + (size_t)c * CHUNK_DW + slot * 4) = v;
}

// Bit-exact numpy npyv(SSE3,no-FMA) einsum; lane-chains split across thread
// quads (l=tid&3), token-pairs in v_pk ops. Barrier-free K loop: per-wave
// private A staging (LDS dbuf), B read directly from the L2-resident image.
__global__ __launch_bounds__(512)
__attribute__((amdgpu_waves_per_eu(4, 4)))
void gate_kernel(
    const float* __restrict__ hid, const float* __restrict__ Bt,
    float* __restrict__ out, float* __restrict__ cnt, float* __restrict__ prb)
{
    __shared__ union {
        float as[8][2][4][SAW];   // [wave][buf][l][(tok>>1)*16 + q*2 + (tok&1)]
        float ls[TM][SL];
    } sh;
    __shared__ float maxS[TM], sumS[TM], invS[TM];

    const int tid  = threadIdx.x;
    const int lane = tid & 63;
    const int w    = tid >> 6;
    const int l    = tid & 3;
    const int eg   = (tid >> 2) & 31;
    const int tg   = tid >> 7;             // token group 0..3 (8 tokens)
    const int h    = w & 1;                // expert half within slab pair
    const int t0   = blockIdx.x * TM;

    f32x2 acc2[4][8];                      // [token-pair][j]
#pragma unroll
    for (int i = 0; i < 4; ++i)
#pragma unroll
        for (int j = 0; j < 8; ++j) acc2[i][j] = (f32x2){0.f, 0.f};

    // per-wave A staging: lane -> (local token, q-octet)
    const int atok = lane >> 3;            // 0..7
    const int aq   = lane & 7;             // 0..7
    const float* ahid = hid + (size_t)(t0 + (w >> 1) * 8 + atok) * KD + 4 * aq;
    float* aswr = &sh.as[w][0][0][(atok >> 1) * 16 + aq * 2 + (atok & 1)];

    // ---- prologue: chunk 0 into buf 0; chunk 1 into regs ----
    float4 av = *(const float4*)(ahid);
    aswr[0] = av.x; aswr[SAW] = av.y; aswr[2 * SAW] = av.z; aswr[3 * SAW] = av.w;
    av = *(const float4*)(ahid + 32);
    int cur = 0;

#pragma unroll 1
    for (int c = 0; c < NCHUNK; ++c) {
        const int nxt = cur ^ 1;
        if (c + 1 < NCHUNK) {
            float* p = aswr + nxt * (4 * SAW);
            p[0] = av.x; p[SAW] = av.y; p[2 * SAW] = av.z; p[3 * SAW] = av.w;
            if (c + 2 < NCHUNK) av = *(const float4*)(ahid + 32 * (c + 2));
        }
        const float* bc  = Bt + (size_t)c * 8192 + h * 256 + (lane << 2);
        const float* arb = &sh.as[w][cur][l][0];

#pragma unroll
        for (int j16 = 0; j16 < 2; ++j16) {        // 16-blocks ascending k
            const float* ar = arb + j16 * 8;
            float4 a0[4], a1[4];
#pragma unroll
            for (int tp = 0; tp < 4; ++tp) {
                a0[tp] = *(const float4*)(ar + tp * 16);       // q0,q1 pairs
                a1[tp] = *(const float4*)(ar + tp * 16 + 4);   // q2,q3 pairs
            }
#pragma unroll
            for (int jh = 0; jh < 2; ++jh) {
                float4 b[4];
#pragma unroll
                for (int jj = 0; jj < 4; ++jj)
                    b[jj] = *(const float4*)(bc + j16 * 4096 + (jh * 4 + jj) * 512);
#pragma unroll
                for (int jj = 0; jj < 4; ++jj) {
                    const int j = jh * 4 + jj;
                    const f32x2 b01 = (f32x2){b[jj].x, b[jj].y};   // {q0,q1}
                    const f32x2 b23 = (f32x2){b[jj].z, b[jj].w};   // {q2,q3}
#pragma unroll
                    for (int tp = 0; tp < 4; ++tp) {
                        const f32x2 aQ0 = (f32x2){a0[tp].x, a0[tp].y};
                        const f32x2 aQ1 = (f32x2){a0[tp].z, a0[tp].w};
                        const f32x2 aQ2 = (f32x2){a1[tp].x, a1[tp].y};
                        const f32x2 aQ3 = (f32x2){a1[tp].z, a1[tp].w};
                        f32x2 s = acc2[tp][j];
                        s = pk_add(pk_mul_hi(aQ3, b23), s);   // q=3
                        s = pk_add(pk_mul_lo(aQ2, b23), s);   // q=2
                        s = pk_add(pk_mul_hi(aQ1, b01), s);   // q=1
                        s = pk_add(pk_mul_lo(aQ0, b01), s);   // q=0
                        acc2[tp][j] = s;
                    }
                }
            }
        }
        cur = nxt;
    }

    // ---- combine lane-chains: (s0+s1)+(s2+s3) per component ----
    __syncthreads();                       // all waves done with sh.as
#pragma unroll
    for (int tp = 0; tp < 4; ++tp)
#pragma unroll
        for (int j = 0; j < 8; ++j) {
            float sx = acc2[tp][j].x, sy = acc2[tp][j].y;
            sx = __fadd_rn(sx, __shfl_xor(sx, 1));
            sx = __fadd_rn(sx, __shfl_xor(sx, 2));
            sy = __fadd_rn(sy, __shfl_xor(sy, 1));
            sy = __fadd_rn(sy, __shfl_xor(sy, 2));
            if (l == 0) {
                sh.ls[tg * 8 + 2 * tp][eg + 32 * j]     = sx;
                sh.ls[tg * 8 + 2 * tp + 1][eg + 32 * j] = sy;
            }
        }
    if (tid < TM) sumS[tid] = 0.f;
    __syncthreads();

    // ---- per-token top-k (threads 0..31), fp32 bit-exact ----
    if (tid < TM) {
        const float* lr = &sh.ls[tid][0];
        float tv[8]; int ti[8];
#pragma unroll
        for (int j = 0; j < 8; ++j) { tv[j] = -1e30f; ti[j] = 0; }
        float rowmax = -1e30f;

        auto ins8 = [&](float v, int idx) {
#pragma unroll
            for (int p = 0; p < 8; ++p) {
                if (v > tv[p]) {
#pragma unroll
                    for (int q = 7; q > p; --q) { tv[q] = tv[q - 1]; ti[q] = ti[q - 1]; }
                    tv[p] = v; ti[p] = idx;
                    break;
                }
            }
        };

#pragma unroll 1
        for (int g = 0; g < 8; ++g) {
            float v0 = -1e30f, v1 = -1e30f, v2 = -1e30f, v3 = -1e30f;
            int   i0 = 0, i1 = 0, i2 = 0, i3 = 0;
            for (int j = 0; j < 32; ++j) {
                const float v = lr[g * 32 + j];
                if (v > v0)      { v3=v2;i3=i2; v2=v1;i2=i1; v1=v0;i1=i0; v0=v;i0=j; }
                else if (v > v1) { v3=v2;i3=i2; v2=v1;i2=i1; v1=v;i1=j; }
                else if (v > v2) { v3=v2;i3=i2; v2=v;i2=j; }
                else if (v > v3) { v3=v;i3=j; }
            }
            rowmax = fmaxf(rowmax, v0);
            ins8(v0, g * 32 + i0);
            ins8(v1, g * 32 + i1);
            ins8(v2, g * 32 + i2);
            ins8(v3, g * 32 + i3);
        }

        const float s01 = __fadd_rn(tv[0], tv[1]);
        const float s23 = __fadd_rn(tv[2], tv[3]);
        const float s45 = __fadd_rn(tv[4], tv[5]);
        const float s67 = __fadd_rn(tv[6], tv[7]);
        float s = __fadd_rn(__fadd_rn(s01, s23), __fadd_rn(s45, s67));
        s = __fadd_rn(s, 1e-20f);

        const size_t tg2 = (size_t)(t0 + tid);
#pragma unroll
        for (int j = 0; j < 8; ++j) {
            out[tg2 * 8 + j]                    = (float)ti[j];
            out[(size_t)NTOK * 8 + tg2 * 8 + j] = __fdiv_rn(tv[j], s);
            atomicAdd(&cnt[ti[j]], 1.0f);
        }
        maxS[tid] = rowmax;
    }
    __syncthreads();

    // ---- per-token softmax denominator (16 threads per token) ----
    {
        const int t  = tid >> 4;
        const int c0 = (tid & 15) * 16;
        const float m = maxS[t];
        float part = 0.f;
#pragma unroll
        for (int j = 0; j < 16; ++j) part += __expf(sh.ls[t][c0 + j] - m);
        atomicAdd(&sumS[t], part);
    }
    __syncthreads();
    if (tid < TM) invS[tid] = 1.0f / sumS[tid];
    __syncthreads();

    // ---- per-expert softmax-prob partial over block tokens ----
    if (tid < NE) {
        float p = 0.f;
#pragma unroll
        for (int n = 0; n < TM; ++n) p += __expf(sh.ls[n][tid] - maxS[n]) * invS[n];
        atomicAdd(&prb[tid], p);
    }
}

__global__ void aux_kernel(const float* __restrict__ cnt,
                           const float* __restrict__ prb,
                           float* __restrict__ out)
{
    const int tid = threadIdx.x;
    float v = cnt[tid] * prb[tid];
#pragma unroll
    for (int off = 32; off; off >>= 1) v += __shfl_down(v, off, 64);
    __shared__ float ps[4];
    if ((tid & 63) == 0) ps[tid >> 6] = v;
    __syncthreads();
    if (tid == 0) {
        const float tot = ps[0] + ps[1] + ps[2] + ps[3];
        out[(size_t)NTOK * 8 * 2] = tot * (0.001f / (131072.0f * 16384.0f));
    }
}

extern "C" void kernel_launch(void* const* d_in, const int* in_sizes, int n_in,
                              void* d_out, int out_size, void* d_ws, size_t ws_size,
                              hipStream_t stream)
{
    (void)in_sizes; (void)n_in; (void)out_size; (void)ws_size;
    const float* hid = (const float*)d_in[0];
    const float* wgt = (const float*)d_in[1];
    float* out = (float*)d_out;
    float* cnt = (float*)d_ws;             // 256 f
    float* prb = cnt + NE;                 // 256 f
    float* Bt  = prb + NE;                 // 2 MB image (16B-aligned offset)

    hipMemsetAsync(d_ws, 0, 2 * NE * sizeof(float), stream);
    transform_kernel<<<512, 256, 0, stream>>>(wgt, Bt);
    gate_kernel<<<NTOK / TM, 512, 0, stream>>>(hid, Bt, out, cnt, prb);
    aux_kernel<<<1, 256, 0, stream>>>(cnt, prb, out);
}